// Round 2
// baseline (99.821 us; speedup 1.0000x reference)
//
#include <hip/hip_runtime.h>

// Depthwise 3x3 ones-kernel conv (overlap-sum), zero-padded, stride 1.
// x: (64, 512, 40, 40) fp32 -> out: same shape.
//
// Zero-LDS, zero-barrier version: 10 lanes own one 40-float row (10 x float4).
// Horizontal 3-sum via 2 shuffles (neighbor lane's .w / .x, masked at edges).
// Vertical 3-sum via rolling 3-register window down the 40 rows.
// Each float4 loaded once, stored once.

#define W 40
#define H 40
#define VEC_PER_ROW 10          // 40 floats / 4
#define PLANE_ELEMS 1600        // 40*40
#define GROUPS_PER_WAVE 6       // 6 groups of 10 lanes; lanes 60..63 idle
#define WAVES_PER_BLOCK 4       // 256 threads
#define PLANES_PER_BLOCK (GROUPS_PER_WAVE * WAVES_PER_BLOCK)  // 24

__global__ __launch_bounds__(256) void overlap_sum_3x3(
    const float* __restrict__ in, float* __restrict__ out, int n_planes)
{
    const int t    = threadIdx.x;
    const int wave = t >> 6;
    const int lane = t & 63;
    const int group = lane / 10;          // 0..6 (6 == idle lanes 60..63)
    const int x4    = lane - group * 10;  // 0..9
    if (group >= GROUPS_PER_WAVE) return;

    const int plane = blockIdx.x * PLANES_PER_BLOCK + wave * GROUPS_PER_WAVE + group;
    if (plane >= n_planes) return;

    const float4* __restrict__ src =
        reinterpret_cast<const float4*>(in + (size_t)plane * PLANE_ELEMS) + x4;
    float4* __restrict__ dst =
        reinterpret_cast<float4*>(out + (size_t)plane * PLANE_ELEMS) + x4;

    const bool has_left  = (x4 != 0);
    const bool has_right = (x4 != VEC_PER_ROW - 1);

    // hsum of one row held as float4; rolling window hm1 (y-1), h0 (y).
    float4 hm1 = make_float4(0.f, 0.f, 0.f, 0.f);
    float4 h0;
    {
        const float4 v = src[0];
        float lf = __shfl_up(v.w, 1);
        float rt = __shfl_down(v.x, 1);
        if (!has_left)  lf = 0.f;
        if (!has_right) rt = 0.f;
        h0.x = lf  + v.x + v.y;
        h0.y = v.x + v.y + v.z;
        h0.z = v.y + v.z + v.w;
        h0.w = v.z + v.w + rt;
    }

    #pragma unroll 4
    for (int y = 1; y < H; ++y) {
        const float4 v = src[y * VEC_PER_ROW];
        float lf = __shfl_up(v.w, 1);
        float rt = __shfl_down(v.x, 1);
        if (!has_left)  lf = 0.f;
        if (!has_right) rt = 0.f;
        float4 h1;
        h1.x = lf  + v.x + v.y;
        h1.y = v.x + v.y + v.z;
        h1.z = v.y + v.z + v.w;
        h1.w = v.z + v.w + rt;

        float4 o;
        o.x = hm1.x + h0.x + h1.x;
        o.y = hm1.y + h0.y + h1.y;
        o.z = hm1.z + h0.z + h1.z;
        o.w = hm1.w + h0.w + h1.w;
        dst[(y - 1) * VEC_PER_ROW] = o;

        hm1 = h0;
        h0  = h1;
    }

    // last row: no row below
    float4 o;
    o.x = hm1.x + h0.x;
    o.y = hm1.y + h0.y;
    o.z = hm1.z + h0.z;
    o.w = hm1.w + h0.w;
    dst[(H - 1) * VEC_PER_ROW] = o;
}

extern "C" void kernel_launch(void* const* d_in, const int* in_sizes, int n_in,
                              void* d_out, int out_size, void* d_ws, size_t ws_size,
                              hipStream_t stream) {
    const float* x = (const float*)d_in[0];
    float* out = (float*)d_out;
    const int n_planes = in_sizes[0] / PLANE_ELEMS;   // 32768
    const int grid = (n_planes + PLANES_PER_BLOCK - 1) / PLANES_PER_BLOCK;  // 1366
    overlap_sum_3x3<<<grid, 256, 0, stream>>>(x, out, n_planes);
}

// Round 3
// 76.866 us; speedup vs baseline: 1.2986x; 1.2986x over previous
//
#include <hip/hip_runtime.h>

// Depthwise 3x3 ones-kernel conv (overlap-sum), zero-padded, stride 1.
// x: (64, 512, 40, 40) fp32 -> out: same shape.
//
// One block per 40x40 plane. Separable stencil, all-float4 LDS traffic:
//   stage (b128 writes) -> bar -> hsum (2 b128 reads, center from reg,
//   b128 write) -> bar -> vsum (2 b128 reads, center from reg) -> store.
// Only 2 barriers; every LDS access is ds_read/write_b128 at 16B lane
// stride (2-way bank aliasing = free on gfx950).

#define NV 400            // float4 per 40x40 plane
#define ROW4 10           // float4 per row

__device__ __forceinline__ float4 hsum4(const float4 c, float lf, float rt) {
    float4 h;
    h.x = lf  + c.x + c.y;
    h.y = c.x + c.y + c.z;
    h.z = c.y + c.z + c.w;
    h.w = c.z + c.w + rt;
    return h;
}

__global__ __launch_bounds__(256) void overlap_sum_3x3(
    const float* __restrict__ in, float* __restrict__ out)
{
    __shared__ float4 s_a[NV];
    __shared__ float4 s_h[NV];

    const int t = threadIdx.x;
    const size_t po = (size_t)blockIdx.x * NV;
    const float4* __restrict__ src = reinterpret_cast<const float4*>(in) + po;
    float4*       __restrict__ dst = reinterpret_cast<float4*>(out) + po;

    // ---- stage plane into LDS, keep values in regs ----
    const bool two = (t < NV - 256);      // threads 0..143 own a 2nd vec4
    float4 v0 = src[t];
    float4 v1;
    s_a[t] = v0;
    if (two) { v1 = src[t + 256]; s_a[t + 256] = v1; }
    __syncthreads();

    // ---- horizontal 3-sum (center from regs, edges via b128 neighbors) ----
    const int x40 = t % ROW4;
    float lf0 = (x40 > 0)        ? s_a[t - 1].w : 0.0f;
    float rt0 = (x40 < ROW4 - 1) ? s_a[t + 1].x : 0.0f;
    float4 h0 = hsum4(v0, lf0, rt0);
    s_h[t] = h0;

    float4 h1;
    if (two) {
        const int j  = t + 256;
        const int x41 = j % ROW4;
        float lf1 = (x41 > 0)        ? s_a[j - 1].w : 0.0f;
        float rt1 = (x41 < ROW4 - 1) ? s_a[j + 1].x : 0.0f;
        h1 = hsum4(v1, lf1, rt1);
        s_h[j] = h1;
    }
    __syncthreads();

    // ---- vertical 3-sum (center from regs) + store ----
    {
        float4 o = h0;
        if (t >= ROW4) {                 // row above exists
            const float4 u = s_h[t - ROW4];
            o.x += u.x; o.y += u.y; o.z += u.z; o.w += u.w;
        }
        // t < 256 <= NV-ROW4, row below always exists for j0
        const float4 d = s_h[t + ROW4];
        o.x += d.x; o.y += d.y; o.z += d.z; o.w += d.w;
        dst[t] = o;
    }
    if (two) {
        const int j = t + 256;           // j in [256,400): row above always exists
        float4 o = h1;
        const float4 u = s_h[j - ROW4];
        o.x += u.x; o.y += u.y; o.z += u.z; o.w += u.w;
        if (j < NV - ROW4) {             // row below exists
            const float4 d = s_h[j + ROW4];
            o.x += d.x; o.y += d.y; o.z += d.z; o.w += d.w;
        }
        dst[j] = o;
    }
}

extern "C" void kernel_launch(void* const* d_in, const int* in_sizes, int n_in,
                              void* d_out, int out_size, void* d_ws, size_t ws_size,
                              hipStream_t stream) {
    const float* x = (const float*)d_in[0];
    float* out = (float*)d_out;
    const int n_planes = in_sizes[0] / (NV * 4);   // 32768 planes
    overlap_sum_3x3<<<n_planes, 256, 0, stream>>>(x, out);
}

// Round 5
// 63.567 us; speedup vs baseline: 1.5703x; 1.2092x over previous
//
#include <hip/hip_runtime.h>

// Depthwise 3x3 ones-kernel conv (overlap-sum), zero-padded, stride 1.
// x: (64, 512, 40, 40) fp32 -> out: same shape.
//
// One block per 40x40 plane. Separable stencil, all-float4 LDS traffic.
// R5: output stored with __builtin_nontemporal_store (gfx950 'nt'
// no-allocate hint) via native clang vector type (HIP_vector_type is
// rejected by the builtin). Goal: write-once output stream doesn't evict
// the input from the 256 MiB Infinity Cache.

#define NV 400            // float4 per 40x40 plane
#define ROW4 10           // float4 per row

typedef float f32x4 __attribute__((ext_vector_type(4)));

__device__ __forceinline__ float4 hsum4(const float4 c, float lf, float rt) {
    float4 h;
    h.x = lf  + c.x + c.y;
    h.y = c.x + c.y + c.z;
    h.z = c.y + c.z + c.w;
    h.w = c.z + c.w + rt;
    return h;
}

__device__ __forceinline__ void nt_store4(float4* p, const float4 v) {
    f32x4 nv;
    nv.x = v.x; nv.y = v.y; nv.z = v.z; nv.w = v.w;
    __builtin_nontemporal_store(nv, reinterpret_cast<f32x4*>(p));
}

__global__ __launch_bounds__(256) void overlap_sum_3x3(
    const float* __restrict__ in, float* __restrict__ out)
{
    __shared__ float4 s_a[NV];
    __shared__ float4 s_h[NV];

    const int t = threadIdx.x;
    const size_t po = (size_t)blockIdx.x * NV;
    const float4* __restrict__ src = reinterpret_cast<const float4*>(in) + po;
    float4*       __restrict__ dst = reinterpret_cast<float4*>(out) + po;

    // ---- stage plane into LDS, keep values in regs ----
    const bool two = (t < NV - 256);      // threads 0..143 own a 2nd vec4
    float4 v0 = src[t];
    float4 v1;
    s_a[t] = v0;
    if (two) { v1 = src[t + 256]; s_a[t + 256] = v1; }
    __syncthreads();

    // ---- horizontal 3-sum (center from regs, edges via b128 neighbors) ----
    const int x40 = t % ROW4;
    float lf0 = (x40 > 0)        ? s_a[t - 1].w : 0.0f;
    float rt0 = (x40 < ROW4 - 1) ? s_a[t + 1].x : 0.0f;
    float4 h0 = hsum4(v0, lf0, rt0);
    s_h[t] = h0;

    float4 h1;
    if (two) {
        const int j  = t + 256;
        const int x41 = j % ROW4;
        float lf1 = (x41 > 0)        ? s_a[j - 1].w : 0.0f;
        float rt1 = (x41 < ROW4 - 1) ? s_a[j + 1].x : 0.0f;
        h1 = hsum4(v1, lf1, rt1);
        s_h[j] = h1;
    }
    __syncthreads();

    // ---- vertical 3-sum (center from regs) + nt store ----
    {
        float4 o = h0;
        if (t >= ROW4) {                 // row above exists
            const float4 u = s_h[t - ROW4];
            o.x += u.x; o.y += u.y; o.z += u.z; o.w += u.w;
        }
        const float4 d = s_h[t + ROW4];  // t < 256 <= NV-ROW4: row below exists
        o.x += d.x; o.y += d.y; o.z += d.z; o.w += d.w;
        nt_store4(&dst[t], o);
    }
    if (two) {
        const int j = t + 256;           // j in [256,400): row above always exists
        float4 o = h1;
        const float4 u = s_h[j - ROW4];
        o.x += u.x; o.y += u.y; o.z += u.z; o.w += u.w;
        if (j < NV - ROW4) {             // row below exists
            const float4 d = s_h[j + ROW4];
            o.x += d.x; o.y += d.y; o.z += d.z; o.w += d.w;
        }
        nt_store4(&dst[j], o);
    }
}

extern "C" void kernel_launch(void* const* d_in, const int* in_sizes, int n_in,
                              void* d_out, int out_size, void* d_ws, size_t ws_size,
                              hipStream_t stream) {
    const float* x = (const float*)d_in[0];
    float* out = (float*)d_out;
    const int n_planes = in_sizes[0] / (NV * 4);   // 32768 planes
    overlap_sum_3x3<<<n_planes, 256, 0, stream>>>(x, out);
}